// Round 7
// baseline (394.325 us; speedup 1.0000x reference)
//
#include <hip/hip_runtime.h>
#include <math.h>

#define S_LEN 512
#define D_IN  768
#define H_DIM 50
#define G4    200
#define NCT   13
#define BROWS 128
#define NTILES 1024      // (256*512)/128
#define KSTEPS 24        // 768/32
#define FR_KS  13312     // ushorts per K-step of frag-packed W (26,624 B)

typedef float   f32x4 __attribute__((ext_vector_type(4)));
typedef short   s16x8 __attribute__((ext_vector_type(8)));
typedef _Float16 f16x2 __attribute__((ext_vector_type(2)));

__device__ ushort g_Wf[KSTEPS * FR_KS];   // [ks][ct][half][lane][8]
__device__ int    g_counter;

__device__ __forceinline__ float fsigmoid(float x) {
    return 1.0f / (1.0f + __expf(-x));
}
__device__ __forceinline__ float ftanh(float x) {
    float ax = fabsf(x);
    float e  = __expf(-2.0f * ax);
    float t  = (1.0f - e) / (1.0f + e);
    return copysignf(t, x);
}

// ---------------------------------------------------------------------------
// prep: pack W_ih into MFMA-frag-linear bf16 hi/lo: g_Wf[ks][ct][half][lane][8]
// ---------------------------------------------------------------------------
__global__ void prep_w(const float* __restrict__ W) {
    int f = blockIdx.x * 256 + threadIdx.x;          // frag id
    if (f == 0) g_counter = 0;
    if (f >= KSTEPS * 26 * 64) return;               // 39936 frags
    const int l  = f & 63;
    const int g  = (f >> 6) % 26;
    const int ks = (f >> 6) / 26;
    const int ct = g >> 1, hf = g & 1;
    const int n  = ct * 16 + (l & 15);
    const int k0 = ks * 32 + (l >> 4) * 8;
    ushort v[8] __attribute__((aligned(16)));
#pragma unroll
    for (int j = 0; j < 8; ++j) v[j] = 0;
    if (n < G4) {
        const float* wp = &W[(size_t)n * D_IN + k0];
#pragma unroll
        for (int j = 0; j < 8; ++j) {
            float xv = wp[j];
            unsigned u = __float_as_uint(xv);
            if (hf == 0) v[j] = (ushort)(u >> 16);
            else {
                float d = xv - __uint_as_float(u & 0xffff0000u);
                v[j] = (ushort)(__float_as_uint(d) >> 16);
            }
        }
    }
    *(uint4*)&g_Wf[(size_t)f * 8] = *(const uint4*)v;
}

__device__ __forceinline__ void pack2(float f0, float f1, unsigned& h, unsigned& l) {
    unsigned u0 = __float_as_uint(f0), u1 = __float_as_uint(f1);
    h = (u0 >> 16) | (u1 & 0xffff0000u);
    float d0 = f0 - __uint_as_float(u0 & 0xffff0000u);
    float d1 = f1 - __uint_as_float(u1 & 0xffff0000u);
    l = (__float_as_uint(d0) >> 16) | (__float_as_uint(d1) & 0xffff0000u);
}

// async-stage one K-step of packed W into LDS (26,624 B).
__device__ __forceinline__ void stage_b(int ks, ushort* dst, int wv, int lane) {
    const ushort* gb = g_Wf + (size_t)ks * FR_KS;
#pragma unroll
    for (int i = 0; i < 7; ++i) {
        const int c0 = i * 2048 + wv * 512;          // ushort units
        if (c0 < FR_KS) {
#if __has_builtin(__builtin_amdgcn_global_load_lds)
            __builtin_amdgcn_global_load_lds(
                (const __attribute__((address_space(1))) unsigned int*)(gb + c0 + lane * 8),
                (__attribute__((address_space(3))) unsigned int*)(dst + c0),
                16, 0, 0);
#else
            *(uint4*)(dst + c0 + (size_t)lane * 8) = *(const uint4*)(gb + c0 + (size_t)lane * 8);
#endif
        }
    }
}

// ---------------------------------------------------------------------------
// xg = x @ W_ih^T, split-bf16 MFMA (AhBh + AlBh + AhBl). Unchanged from R6.
// ---------------------------------------------------------------------------
__global__ __launch_bounds__(256, 2) void gemm_xg(
    const float* __restrict__ x, const int* __restrict__ mask,
    float* __restrict__ xg)
{
    __shared__ ushort Bs[2][FR_KS];                  // 53,248 B
    __shared__ int tile_sh;
    const int tid  = threadIdx.x;
    const int wv   = tid >> 6;
    const int lane = tid & 63;
    const int lr   = lane & 15;
    const int kch  = (lane >> 4) * 8;

    for (;;) {
        if (tid == 0) tile_sh = atomicAdd(&g_counter, 1);
        __syncthreads();
        const int tile = tile_sh;
        __syncthreads();
        if (tile >= NTILES) return;

        const int row0 = tile * BROWS;
        const int b    = row0 >> 9;
        const int t0   = row0 & (S_LEN - 1);
        if (mask[b * S_LEN + t0] == 0) continue;     // whole tile past length[b]
        const bool live = mask[b * S_LEN + t0 + wv * 32] != 0;

        const int r0 = row0 + wv * 32;
        const float* xr0 = x + (size_t)(r0 + lr) * D_IN;
        const float* xr1 = xr0 + (size_t)16 * D_IN;

        f32x4 acc0[NCT], acc1[NCT];
#pragma unroll
        for (int i = 0; i < NCT; ++i) {
            acc0[i] = (f32x4){0.f, 0.f, 0.f, 0.f};
            acc1[i] = (f32x4){0.f, 0.f, 0.f, 0.f};
        }
        float4 ac0 = {0,0,0,0}, ac1 = {0,0,0,0}, ac2 = {0,0,0,0}, ac3 = {0,0,0,0};
        float4 an0 = {0,0,0,0}, an1 = {0,0,0,0}, an2 = {0,0,0,0}, an3 = {0,0,0,0};

        stage_b(0, Bs[0], wv, lane);
        if (live) {
            ac0 = *(const float4*)(xr0 + kch);
            ac1 = *(const float4*)(xr0 + kch + 4);
            ac2 = *(const float4*)(xr1 + kch);
            ac3 = *(const float4*)(xr1 + kch + 4);
        }
        __syncthreads();                             // Bs[0] staged & drained

        for (int ks = 0; ks < KSTEPS; ++ks) {
            if (ks < KSTEPS - 1) {
                stage_b(ks + 1, Bs[(ks + 1) & 1], wv, lane);
                if (live) {
                    const int k1 = (ks + 1) * 32 + kch;
                    an0 = *(const float4*)(xr0 + k1);
                    an1 = *(const float4*)(xr0 + k1 + 4);
                    an2 = *(const float4*)(xr1 + k1);
                    an3 = *(const float4*)(xr1 + k1 + 4);
                }
            }
            if (live) {
                uint4 h0, l0, h1, l1;
                pack2(ac0.x, ac0.y, h0.x, l0.x); pack2(ac0.z, ac0.w, h0.y, l0.y);
                pack2(ac1.x, ac1.y, h0.z, l0.z); pack2(ac1.z, ac1.w, h0.w, l0.w);
                pack2(ac2.x, ac2.y, h1.x, l1.x); pack2(ac2.z, ac2.w, h1.y, l1.y);
                pack2(ac3.x, ac3.y, h1.z, l1.z); pack2(ac3.z, ac3.w, h1.w, l1.w);
                s16x8 A0h = *(s16x8*)&h0, A0l = *(s16x8*)&l0;
                s16x8 A1h = *(s16x8*)&h1, A1l = *(s16x8*)&l1;
                const ushort* bp = &Bs[ks & 1][lane * 8];
#pragma unroll
                for (int ct = 0; ct < NCT; ++ct) {
                    s16x8 Bh = *(const s16x8*)(bp + ct * 1024);
                    s16x8 Bl = *(const s16x8*)(bp + ct * 1024 + 512);
                    acc0[ct] = __builtin_amdgcn_mfma_f32_16x16x32_bf16(A0h, Bh, acc0[ct], 0, 0, 0);
                    acc0[ct] = __builtin_amdgcn_mfma_f32_16x16x32_bf16(A0l, Bh, acc0[ct], 0, 0, 0);
                    acc0[ct] = __builtin_amdgcn_mfma_f32_16x16x32_bf16(A0h, Bl, acc0[ct], 0, 0, 0);
                    acc1[ct] = __builtin_amdgcn_mfma_f32_16x16x32_bf16(A1h, Bh, acc1[ct], 0, 0, 0);
                    acc1[ct] = __builtin_amdgcn_mfma_f32_16x16x32_bf16(A1l, Bh, acc1[ct], 0, 0, 0);
                    acc1[ct] = __builtin_amdgcn_mfma_f32_16x16x32_bf16(A1h, Bl, acc1[ct], 0, 0, 0);
                }
            }
            ac0 = an0; ac1 = an1; ac2 = an2; ac3 = an3;
            __syncthreads();                         // readers done; stage(ks+1) drained
        }

        if (live) {
            const int orow = r0 + (lane >> 4) * 4;
            const int ocol = lane & 15;
#pragma unroll
            for (int ct = 0; ct < NCT; ++ct) {
                const int col = ct * 16 + ocol;
                if (col < G4) {
#pragma unroll
                    for (int e = 0; e < 4; ++e) {
                        xg[(size_t)(orow + e) * G4 + col]      = acc0[ct][e];
                        xg[(size_t)(orow + 16 + e) * G4 + col] = acc1[ct][e];
                    }
                }
            }
        }
    }
}

// ---------------------------------------------------------------------------
// LSTM scan: ONE WAVE per batch, zero barriers. Weights pinned in VGPRs via
// empty asm (R6 showed VGPR=76 < the 100 needed -> compiler rematerialized
// the W_hh loads inside the step loop, ~100 un-hidden L2 loads/step).
// ---------------------------------------------------------------------------
__global__ __launch_bounds__(64, 1) void lstm_scan(
    const float* __restrict__ xgp, const int* __restrict__ mask,
    const float* __restrict__ W_hh, const float* __restrict__ b_ih,
    const float* __restrict__ b_hh, const float* __restrict__ W_cls,
    const float* __restrict__ b_cls, float* __restrict__ out)
{
    const int b = blockIdx.x;
    const int l = threadIdx.x;

    int s = 0;
#pragma unroll
    for (int k = 0; k < 8; ++k) s += mask[b * S_LEN + l + 64 * k];
#pragma unroll
    for (int off = 1; off < 64; off <<= 1) s += __shfl_xor(s, off, 64);
    const int len = s;                               // >= 1

    const bool act = (l < H_DIM);
    f16x2 wi2[25], wf2[25], wg2[25], wo2[25];
#pragma unroll
    for (int q = 0; q < 25; ++q) {
        if (act) {
            const float* p0 = &W_hh[(size_t)l * H_DIM + 2 * q];
            const float* p1 = &W_hh[(size_t)(50 + l) * H_DIM + 2 * q];
            const float* p2 = &W_hh[(size_t)(100 + l) * H_DIM + 2 * q];
            const float* p3 = &W_hh[(size_t)(150 + l) * H_DIM + 2 * q];
            wi2[q] = (f16x2){(_Float16)p0[0], (_Float16)p0[1]};
            wf2[q] = (f16x2){(_Float16)p1[0], (_Float16)p1[1]};
            wg2[q] = (f16x2){(_Float16)p2[0], (_Float16)p2[1]};
            wo2[q] = (f16x2){(_Float16)p3[0], (_Float16)p3[1]};
        } else {
            wi2[q] = (f16x2){0, 0}; wf2[q] = (f16x2){0, 0};
            wg2[q] = (f16x2){0, 0}; wo2[q] = (f16x2){0, 0};
        }
    }
    // Pin each weight value as an opaque register: rematerialization from
    // W_hh becomes impossible; ~500 free VGPRs at 1 wave/CU so no spill.
#pragma unroll
    for (int q = 0; q < 25; ++q) {
        unsigned u0 = __builtin_bit_cast(unsigned, wi2[q]);
        unsigned u1 = __builtin_bit_cast(unsigned, wf2[q]);
        unsigned u2 = __builtin_bit_cast(unsigned, wg2[q]);
        unsigned u3 = __builtin_bit_cast(unsigned, wo2[q]);
        asm volatile("" : "+v"(u0), "+v"(u1), "+v"(u2), "+v"(u3));
        wi2[q] = __builtin_bit_cast(f16x2, u0);
        wf2[q] = __builtin_bit_cast(f16x2, u1);
        wg2[q] = __builtin_bit_cast(f16x2, u2);
        wo2[q] = __builtin_bit_cast(f16x2, u3);
    }
    const float bi = act ? b_ih[l]           + b_hh[l]           : 0.f;
    const float bf = act ? b_ih[50 + l]      + b_hh[50 + l]      : 0.f;
    const float bg = act ? b_ih[100 + l]     + b_hh[100 + l]     : 0.f;
    const float bo = act ? b_ih[150 + l]     + b_hh[150 + l]     : 0.f;

    float h = 0.f, c = 0.f;
    const float* xgb = xgp + (size_t)b * S_LEN * G4;

    auto ld = [&](int t, float& xi, float& xf, float& xq, float& xo) {
        if (act && t < len) {
            const float* pp = xgb + (size_t)t * G4 + l;
            xi = pp[0]; xf = pp[50]; xq = pp[100]; xo = pp[150];
        }
    };
    float xiA=0,xfA=0,xqA=0,xoA=0, xiB=0,xfB=0,xqB=0,xoB=0;
    float xiC=0,xfC=0,xqC=0,xoC=0, xiD=0,xfD=0,xqD=0,xoD=0;
    ld(0, xiA, xfA, xqA, xoA); ld(1, xiB, xfB, xqB, xoB);
    ld(2, xiC, xfC, xqC, xoC); ld(3, xiD, xfD, xqD, xoD);

#if __has_builtin(__builtin_amdgcn_fdot2)
#define FDOT2(a, b, cc) __builtin_amdgcn_fdot2((a), (b), (cc), false)
#else
#define FDOT2(a, b, cc) ((cc) + (float)(a)[0] * (float)(b)[0] + (float)(a)[1] * (float)(b)[1])
#endif

    auto step = [&](int t, float& xi, float& xf, float& xq, float& xo) {
        int pa = __builtin_amdgcn_ds_bpermute(8 * l,     __float_as_int(h));
        int pb = __builtin_amdgcn_ds_bpermute(8 * l + 4, __float_as_int(h));
#if __has_builtin(__builtin_amdgcn_cvt_pkrtz)
        f16x2 hp = __builtin_bit_cast(f16x2,
            __builtin_amdgcn_cvt_pkrtz(__int_as_float(pa), __int_as_float(pb)));
#else
        f16x2 hp = (f16x2){(_Float16)__int_as_float(pa), (_Float16)__int_as_float(pb)};
#endif
        unsigned hu = __builtin_bit_cast(unsigned, hp);

        float ai = xi + bi, af = xf + bf, aq = xq + bg, ao = xo + bo;
        ld(t + 4, xi, xf, xq, xo);                   // prefetch into this set
#pragma unroll
        for (int q = 0; q < 25; ++q) {
            unsigned r = (unsigned)__builtin_amdgcn_readlane((int)hu, q);
            f16x2 hq = __builtin_bit_cast(f16x2, r);
            ai = FDOT2(hq, wi2[q], ai);
            af = FDOT2(hq, wf2[q], af);
            aq = FDOT2(hq, wg2[q], aq);
            ao = FDOT2(hq, wo2[q], ao);
        }
        float ig = fsigmoid(ai), fg = fsigmoid(af);
        float gg = ftanh(aq),    og = fsigmoid(ao);
        if (act) {
            c = fg * c + ig * gg;
            h = og * ftanh(c);
        }
    };

    int t = 0;
    while (t < len) {
        step(t, xiA, xfA, xqA, xoA); ++t; if (t >= len) break;
        step(t, xiB, xfB, xqB, xoB); ++t; if (t >= len) break;
        step(t, xiC, xfC, xqC, xoC); ++t; if (t >= len) break;
        step(t, xiD, xfD, xqD, xoD); ++t;
    }
#undef FDOT2

    float p0 = act ? h * W_cls[l]          : 0.f;
    float p1 = act ? h * W_cls[H_DIM + l]  : 0.f;
#pragma unroll
    for (int off = 1; off < 64; off <<= 1) {
        p0 += __shfl_xor(p0, off, 64);
        p1 += __shfl_xor(p1, off, 64);
    }
    if (l == 0) {
        out[2 * b]     = p0 + b_cls[0];
        out[2 * b + 1] = p1 + b_cls[1];
    }
}

extern "C" void kernel_launch(void* const* d_in, const int* in_sizes, int n_in,
                              void* d_out, int out_size, void* d_ws, size_t ws_size,
                              hipStream_t stream) {
    const float* x     = (const float*)d_in[0];
    const int*   mask  = (const int*)  d_in[1];
    const float* W_ih  = (const float*)d_in[2];
    const float* W_hh  = (const float*)d_in[3];
    const float* b_ih  = (const float*)d_in[4];
    const float* b_hh  = (const float*)d_in[5];
    const float* W_cls = (const float*)d_in[6];
    const float* b_cls = (const float*)d_in[7];
    float* out = (float*)d_out;
    float* xg  = (float*)d_ws;                       // 104.9 MB

    hipLaunchKernelGGL(prep_w, dim3(156), dim3(256), 0, stream, W_ih);
    hipLaunchKernelGGL(gemm_xg, dim3(512), dim3(256), 0, stream, x, mask, xg);
    hipLaunchKernelGGL(lstm_scan, dim3(256), dim3(64), 0, stream,
                       xg, mask, W_hh, b_ih, b_hh, W_cls, b_cls, out);
}

// Round 8
// 387.508 us; speedup vs baseline: 1.0176x; 1.0176x over previous
//
#include <hip/hip_runtime.h>
#include <math.h>

#define S_LEN 512
#define D_IN  768
#define H_DIM 50
#define G4    200
#define NCT   13
#define BROWS 128
#define NTILES 1024      // (256*512)/128
#define KSTEPS 24        // 768/32
#define FR_KS  13312     // ushorts per K-step of frag-packed W (26,624 B)

typedef float   f32x4 __attribute__((ext_vector_type(4)));
typedef short   s16x8 __attribute__((ext_vector_type(8)));
typedef _Float16 f16x2 __attribute__((ext_vector_type(2)));

__device__ ushort g_Wf[KSTEPS * FR_KS];   // [ks][ct][half][lane][8]
__device__ int    g_counter;

__device__ __forceinline__ float fsigmoid(float x) {
    return 1.0f / (1.0f + __expf(-x));
}
__device__ __forceinline__ float ftanh(float x) {
    float ax = fabsf(x);
    float e  = __expf(-2.0f * ax);
    float t  = (1.0f - e) / (1.0f + e);
    return copysignf(t, x);
}

// ---------------------------------------------------------------------------
// prep: pack W_ih into MFMA-frag-linear bf16 hi/lo: g_Wf[ks][ct][half][lane][8]
// ---------------------------------------------------------------------------
__global__ void prep_w(const float* __restrict__ W) {
    int f = blockIdx.x * 256 + threadIdx.x;          // frag id
    if (f == 0) g_counter = 0;
    if (f >= KSTEPS * 26 * 64) return;               // 39936 frags
    const int l  = f & 63;
    const int g  = (f >> 6) % 26;
    const int ks = (f >> 6) / 26;
    const int ct = g >> 1, hf = g & 1;
    const int n  = ct * 16 + (l & 15);
    const int k0 = ks * 32 + (l >> 4) * 8;
    ushort v[8] __attribute__((aligned(16)));
#pragma unroll
    for (int j = 0; j < 8; ++j) v[j] = 0;
    if (n < G4) {
        const float* wp = &W[(size_t)n * D_IN + k0];
#pragma unroll
        for (int j = 0; j < 8; ++j) {
            float xv = wp[j];
            unsigned u = __float_as_uint(xv);
            if (hf == 0) v[j] = (ushort)(u >> 16);
            else {
                float d = xv - __uint_as_float(u & 0xffff0000u);
                v[j] = (ushort)(__float_as_uint(d) >> 16);
            }
        }
    }
    *(uint4*)&g_Wf[(size_t)f * 8] = *(const uint4*)v;
}

__device__ __forceinline__ void pack2(float f0, float f1, unsigned& h, unsigned& l) {
    unsigned u0 = __float_as_uint(f0), u1 = __float_as_uint(f1);
    h = (u0 >> 16) | (u1 & 0xffff0000u);
    float d0 = f0 - __uint_as_float(u0 & 0xffff0000u);
    float d1 = f1 - __uint_as_float(u1 & 0xffff0000u);
    l = (__float_as_uint(d0) >> 16) | (__float_as_uint(d1) & 0xffff0000u);
}

// async-stage one K-step of packed W into LDS (26,624 B).
__device__ __forceinline__ void stage_b(int ks, ushort* dst, int wv, int lane) {
    const ushort* gb = g_Wf + (size_t)ks * FR_KS;
#pragma unroll
    for (int i = 0; i < 7; ++i) {
        const int c0 = i * 2048 + wv * 512;          // ushort units
        if (c0 < FR_KS) {
#if __has_builtin(__builtin_amdgcn_global_load_lds)
            __builtin_amdgcn_global_load_lds(
                (const __attribute__((address_space(1))) unsigned int*)(gb + c0 + lane * 8),
                (__attribute__((address_space(3))) unsigned int*)(dst + c0),
                16, 0, 0);
#else
            *(uint4*)(dst + c0 + (size_t)lane * 8) = *(const uint4*)(gb + c0 + (size_t)lane * 8);
#endif
        }
    }
}

// ---------------------------------------------------------------------------
// xg = x @ W_ih^T, split-bf16 MFMA (AhBh + AlBh + AhBl). Unchanged from R6.
// ---------------------------------------------------------------------------
__global__ __launch_bounds__(256, 2) void gemm_xg(
    const float* __restrict__ x, const int* __restrict__ mask,
    float* __restrict__ xg)
{
    __shared__ ushort Bs[2][FR_KS];                  // 53,248 B
    __shared__ int tile_sh;
    const int tid  = threadIdx.x;
    const int wv   = tid >> 6;
    const int lane = tid & 63;
    const int lr   = lane & 15;
    const int kch  = (lane >> 4) * 8;

    for (;;) {
        if (tid == 0) tile_sh = atomicAdd(&g_counter, 1);
        __syncthreads();
        const int tile = tile_sh;
        __syncthreads();
        if (tile >= NTILES) return;

        const int row0 = tile * BROWS;
        const int b    = row0 >> 9;
        const int t0   = row0 & (S_LEN - 1);
        if (mask[b * S_LEN + t0] == 0) continue;     // whole tile past length[b]
        const bool live = mask[b * S_LEN + t0 + wv * 32] != 0;

        const int r0 = row0 + wv * 32;
        const float* xr0 = x + (size_t)(r0 + lr) * D_IN;
        const float* xr1 = xr0 + (size_t)16 * D_IN;

        f32x4 acc0[NCT], acc1[NCT];
#pragma unroll
        for (int i = 0; i < NCT; ++i) {
            acc0[i] = (f32x4){0.f, 0.f, 0.f, 0.f};
            acc1[i] = (f32x4){0.f, 0.f, 0.f, 0.f};
        }
        float4 ac0 = {0,0,0,0}, ac1 = {0,0,0,0}, ac2 = {0,0,0,0}, ac3 = {0,0,0,0};
        float4 an0 = {0,0,0,0}, an1 = {0,0,0,0}, an2 = {0,0,0,0}, an3 = {0,0,0,0};

        stage_b(0, Bs[0], wv, lane);
        if (live) {
            ac0 = *(const float4*)(xr0 + kch);
            ac1 = *(const float4*)(xr0 + kch + 4);
            ac2 = *(const float4*)(xr1 + kch);
            ac3 = *(const float4*)(xr1 + kch + 4);
        }
        __syncthreads();                             // Bs[0] staged & drained

        for (int ks = 0; ks < KSTEPS; ++ks) {
            if (ks < KSTEPS - 1) {
                stage_b(ks + 1, Bs[(ks + 1) & 1], wv, lane);
                if (live) {
                    const int k1 = (ks + 1) * 32 + kch;
                    an0 = *(const float4*)(xr0 + k1);
                    an1 = *(const float4*)(xr0 + k1 + 4);
                    an2 = *(const float4*)(xr1 + k1);
                    an3 = *(const float4*)(xr1 + k1 + 4);
                }
            }
            if (live) {
                uint4 h0, l0, h1, l1;
                pack2(ac0.x, ac0.y, h0.x, l0.x); pack2(ac0.z, ac0.w, h0.y, l0.y);
                pack2(ac1.x, ac1.y, h0.z, l0.z); pack2(ac1.z, ac1.w, h0.w, l0.w);
                pack2(ac2.x, ac2.y, h1.x, l1.x); pack2(ac2.z, ac2.w, h1.y, l1.y);
                pack2(ac3.x, ac3.y, h1.z, l1.z); pack2(ac3.z, ac3.w, h1.w, l1.w);
                s16x8 A0h = *(s16x8*)&h0, A0l = *(s16x8*)&l0;
                s16x8 A1h = *(s16x8*)&h1, A1l = *(s16x8*)&l1;
                const ushort* bp = &Bs[ks & 1][lane * 8];
#pragma unroll
                for (int ct = 0; ct < NCT; ++ct) {
                    s16x8 Bh = *(const s16x8*)(bp + ct * 1024);
                    s16x8 Bl = *(const s16x8*)(bp + ct * 1024 + 512);
                    acc0[ct] = __builtin_amdgcn_mfma_f32_16x16x32_bf16(A0h, Bh, acc0[ct], 0, 0, 0);
                    acc0[ct] = __builtin_amdgcn_mfma_f32_16x16x32_bf16(A0l, Bh, acc0[ct], 0, 0, 0);
                    acc0[ct] = __builtin_amdgcn_mfma_f32_16x16x32_bf16(A0h, Bl, acc0[ct], 0, 0, 0);
                    acc1[ct] = __builtin_amdgcn_mfma_f32_16x16x32_bf16(A1h, Bh, acc1[ct], 0, 0, 0);
                    acc1[ct] = __builtin_amdgcn_mfma_f32_16x16x32_bf16(A1l, Bh, acc1[ct], 0, 0, 0);
                    acc1[ct] = __builtin_amdgcn_mfma_f32_16x16x32_bf16(A1h, Bl, acc1[ct], 0, 0, 0);
                }
            }
            ac0 = an0; ac1 = an1; ac2 = an2; ac3 = an3;
            __syncthreads();                         // readers done; stage(ks+1) drained
        }

        if (live) {
            const int orow = r0 + (lane >> 4) * 4;
            const int ocol = lane & 15;
#pragma unroll
            for (int ct = 0; ct < NCT; ++ct) {
                const int col = ct * 16 + ocol;
                if (col < G4) {
#pragma unroll
                    for (int e = 0; e < 4; ++e) {
                        xg[(size_t)(orow + e) * G4 + col]      = acc0[ct][e];
                        xg[(size_t)(orow + 16 + e) * G4 + col] = acc1[ct][e];
                    }
                }
            }
        }
    }
}

// ---------------------------------------------------------------------------
// LSTM scan: ONE WAVE per batch, zero barriers. R6/R7 kept the 4x25 f16x2
// weight ARRAYS in scratch (VGPR=76, ~100 scratch reads/step, 258 us).
// Fix per rule #20: 100 NAMED scalar registers via macro expansion -- no
// array object exists, every access is compile-time-static.
// ---------------------------------------------------------------------------
#define REP25(M) M(0) M(1) M(2) M(3) M(4) M(5) M(6) M(7) M(8) M(9) \
                 M(10) M(11) M(12) M(13) M(14) M(15) M(16) M(17) M(18) M(19) \
                 M(20) M(21) M(22) M(23) M(24)

__device__ __forceinline__ unsigned pk2f16(float a, float b) {
#if __has_builtin(__builtin_amdgcn_cvt_pkrtz)
    return __builtin_bit_cast(unsigned, __builtin_amdgcn_cvt_pkrtz(a, b));
#else
    f16x2 v = {(_Float16)a, (_Float16)b};
    return __builtin_bit_cast(unsigned, v);
#endif
}

#if __has_builtin(__builtin_amdgcn_fdot2)
#define FD(hu_, wu_, cc_) __builtin_amdgcn_fdot2( \
    __builtin_bit_cast(f16x2, (hu_)), __builtin_bit_cast(f16x2, (wu_)), (cc_), false)
#else
#define FD(hu_, wu_, cc_) ((cc_) \
    + (float)__builtin_bit_cast(f16x2, (hu_))[0] * (float)__builtin_bit_cast(f16x2, (wu_))[0] \
    + (float)__builtin_bit_cast(f16x2, (hu_))[1] * (float)__builtin_bit_cast(f16x2, (wu_))[1])
#endif

__global__ __launch_bounds__(64, 1) void lstm_scan(
    const float* __restrict__ xgp, const int* __restrict__ mask,
    const float* __restrict__ W_hh, const float* __restrict__ b_ih,
    const float* __restrict__ b_hh, const float* __restrict__ W_cls,
    const float* __restrict__ b_cls, float* __restrict__ out)
{
    const int b = blockIdx.x;
    const int l = threadIdx.x;

    int s = 0;
#pragma unroll
    for (int k = 0; k < 8; ++k) s += mask[b * S_LEN + l + 64 * k];
#pragma unroll
    for (int off = 1; off < 64; off <<= 1) s += __shfl_xor(s, off, 64);
    const int len = s;                               // >= 1

    const bool act = (l < H_DIM);
    const int  ll  = act ? l : 0;                    // keep W_hh rows in-bounds
    const float* wr0 = W_hh + (size_t)ll * H_DIM;
    const float* wr1 = W_hh + (size_t)(50 + ll) * H_DIM;
    const float* wr2 = W_hh + (size_t)(100 + ll) * H_DIM;
    const float* wr3 = W_hh + (size_t)(150 + ll) * H_DIM;

#define WDECL(q) unsigned wi_##q, wf_##q, wg_##q, wo_##q;
    REP25(WDECL)
#undef WDECL
#define WLOAD(q) \
    wi_##q = pk2f16(wr0[2*q], wr0[2*q+1]); \
    wf_##q = pk2f16(wr1[2*q], wr1[2*q+1]); \
    wg_##q = pk2f16(wr2[2*q], wr2[2*q+1]); \
    wo_##q = pk2f16(wr3[2*q], wr3[2*q+1]);
    REP25(WLOAD)
#undef WLOAD
#define WPIN(q) asm volatile("" : "+v"(wi_##q), "+v"(wf_##q), "+v"(wg_##q), "+v"(wo_##q));
    REP25(WPIN)
#undef WPIN

    const float bi = act ? b_ih[l]           + b_hh[l]           : 0.f;
    const float bf = act ? b_ih[50 + l]      + b_hh[50 + l]      : 0.f;
    const float bg = act ? b_ih[100 + l]     + b_hh[100 + l]     : 0.f;
    const float bo = act ? b_ih[150 + l]     + b_hh[150 + l]     : 0.f;

    float h = 0.f, c = 0.f;
    const float* xgb = xgp + (size_t)b * S_LEN * G4;

    auto ld = [&](int t, float& xi, float& xf, float& xq, float& xo) {
        if (act && t < len) {
            const float* pp = xgb + (size_t)t * G4 + l;
            xi = pp[0]; xf = pp[50]; xq = pp[100]; xo = pp[150];
        }
    };
    float xiA=0,xfA=0,xqA=0,xoA=0, xiB=0,xfB=0,xqB=0,xoB=0;
    float xiC=0,xfC=0,xqC=0,xoC=0, xiD=0,xfD=0,xqD=0,xoD=0;
    ld(0, xiA, xfA, xqA, xoA); ld(1, xiB, xfB, xqB, xoB);
    ld(2, xiC, xfC, xqC, xoC); ld(3, xiD, xfD, xqD, xoD);

    auto step = [&](int t, float& xi, float& xf, float& xq, float& xo) {
        // build this lane's h-pair (h[2l], h[2l+1]); broadcast via readlane
        int pa = __builtin_amdgcn_ds_bpermute(8 * l,     __float_as_int(h));
        int pb = __builtin_amdgcn_ds_bpermute(8 * l + 4, __float_as_int(h));
        unsigned hu = pk2f16(__int_as_float(pa), __int_as_float(pb));

        float ai = xi + bi, af = xf + bf, aq = xq + bg, ao = xo + bo;
        ld(t + 4, xi, xf, xq, xo);                   // prefetch into this set
#define DOT(q) { \
        unsigned r_ = (unsigned)__builtin_amdgcn_readlane((int)hu, q); \
        ai = FD(r_, wi_##q, ai); af = FD(r_, wf_##q, af); \
        aq = FD(r_, wg_##q, aq); ao = FD(r_, wo_##q, ao); }
        REP25(DOT)
#undef DOT
        float ig = fsigmoid(ai), fg = fsigmoid(af);
        float gg = ftanh(aq),    og = fsigmoid(ao);
        if (act) {
            c = fg * c + ig * gg;
            h = og * ftanh(c);
        }
    };

    int t = 0;
    while (t < len) {
        step(t, xiA, xfA, xqA, xoA); ++t; if (t >= len) break;
        step(t, xiB, xfB, xqB, xoB); ++t; if (t >= len) break;
        step(t, xiC, xfC, xqC, xoC); ++t; if (t >= len) break;
        step(t, xiD, xfD, xqD, xoD); ++t;
    }

    float p0 = act ? h * W_cls[l]          : 0.f;
    float p1 = act ? h * W_cls[H_DIM + l]  : 0.f;
#pragma unroll
    for (int off = 1; off < 64; off <<= 1) {
        p0 += __shfl_xor(p0, off, 64);
        p1 += __shfl_xor(p1, off, 64);
    }
    if (l == 0) {
        out[2 * b]     = p0 + b_cls[0];
        out[2 * b + 1] = p1 + b_cls[1];
    }
}

extern "C" void kernel_launch(void* const* d_in, const int* in_sizes, int n_in,
                              void* d_out, int out_size, void* d_ws, size_t ws_size,
                              hipStream_t stream) {
    const float* x     = (const float*)d_in[0];
    const int*   mask  = (const int*)  d_in[1];
    const float* W_ih  = (const float*)d_in[2];
    const float* W_hh  = (const float*)d_in[3];
    const float* b_ih  = (const float*)d_in[4];
    const float* b_hh  = (const float*)d_in[5];
    const float* W_cls = (const float*)d_in[6];
    const float* b_cls = (const float*)d_in[7];
    float* out = (float*)d_out;
    float* xg  = (float*)d_ws;                       // 104.9 MB

    hipLaunchKernelGGL(prep_w, dim3(156), dim3(256), 0, stream, W_ih);
    hipLaunchKernelGGL(gemm_xg, dim3(512), dim3(256), 0, stream, x, mask, xg);
    hipLaunchKernelGGL(lstm_scan, dim3(256), dim3(64), 0, stream,
                       xg, mask, W_hh, b_ih, b_hh, W_cls, b_cls, out);
}

// Round 9
// 338.884 us; speedup vs baseline: 1.1636x; 1.1435x over previous
//
#include <hip/hip_runtime.h>
#include <math.h>

#define S_LEN 512
#define D_IN  768
#define H_DIM 50
#define G4    200
#define NCT   13
#define BROWS 128
#define NTILES 1024      // (256*512)/128
#define KSTEPS 24        // 768/32
#define FR_KS  13312     // ushorts per K-step of frag-packed W (26,624 B)

typedef float   f32x4 __attribute__((ext_vector_type(4)));
typedef short   s16x8 __attribute__((ext_vector_type(8)));
typedef _Float16 f16x2 __attribute__((ext_vector_type(2)));

__device__ ushort g_Wf[KSTEPS * FR_KS];   // [ks][ct][half][lane][8]
__device__ int    g_counter;

#define LOG2E 1.44269504f

__device__ __forceinline__ float fexp2(float x) {
#if __has_builtin(__builtin_amdgcn_exp2f)
    return __builtin_amdgcn_exp2f(x);
#else
    return exp2f(x);
#endif
}
__device__ __forceinline__ float frcp(float x) {
#if __has_builtin(__builtin_amdgcn_rcpf)
    return __builtin_amdgcn_rcpf(x);
#else
    return 1.0f / x;
#endif
}
// sigmoid = rcp(1 + 2^(-x*log2e)): mul, exp, add, rcp -- no IEEE divide
__device__ __forceinline__ float fsigmoid(float x) {
    return frcp(1.0f + fexp2(-LOG2E * x));
}
// tanh(x) = sign(x) * (1-e)/(1+e), e = 2^(-2*log2e*|x|)
__device__ __forceinline__ float ftanh(float x) {
    float ax = __builtin_fabsf(x);
    float e  = fexp2(-2.0f * LOG2E * ax);
    float t  = (1.0f - e) * frcp(1.0f + e);
    return __builtin_copysignf(t, x);
}

// ---------------------------------------------------------------------------
// prep: pack W_ih into MFMA-frag-linear bf16 hi/lo: g_Wf[ks][ct][half][lane][8]
// ---------------------------------------------------------------------------
__global__ void prep_w(const float* __restrict__ W) {
    int f = blockIdx.x * 256 + threadIdx.x;          // frag id
    if (f == 0) g_counter = 0;
    if (f >= KSTEPS * 26 * 64) return;               // 39936 frags
    const int l  = f & 63;
    const int g  = (f >> 6) % 26;
    const int ks = (f >> 6) / 26;
    const int ct = g >> 1, hf = g & 1;
    const int n  = ct * 16 + (l & 15);
    const int k0 = ks * 32 + (l >> 4) * 8;
    ushort v[8] __attribute__((aligned(16)));
#pragma unroll
    for (int j = 0; j < 8; ++j) v[j] = 0;
    if (n < G4) {
        const float* wp = &W[(size_t)n * D_IN + k0];
#pragma unroll
        for (int j = 0; j < 8; ++j) {
            float xv = wp[j];
            unsigned u = __float_as_uint(xv);
            if (hf == 0) v[j] = (ushort)(u >> 16);
            else {
                float d = xv - __uint_as_float(u & 0xffff0000u);
                v[j] = (ushort)(__float_as_uint(d) >> 16);
            }
        }
    }
    *(uint4*)&g_Wf[(size_t)f * 8] = *(const uint4*)v;
}

__device__ __forceinline__ void pack2(float f0, float f1, unsigned& h, unsigned& l) {
    unsigned u0 = __float_as_uint(f0), u1 = __float_as_uint(f1);
    h = (u0 >> 16) | (u1 & 0xffff0000u);
    float d0 = f0 - __uint_as_float(u0 & 0xffff0000u);
    float d1 = f1 - __uint_as_float(u1 & 0xffff0000u);
    l = (__float_as_uint(d0) >> 16) | (__float_as_uint(d1) & 0xffff0000u);
}

// async-stage one K-step of packed W into LDS (26,624 B).
__device__ __forceinline__ void stage_b(int ks, ushort* dst, int wv, int lane) {
    const ushort* gb = g_Wf + (size_t)ks * FR_KS;
#pragma unroll
    for (int i = 0; i < 7; ++i) {
        const int c0 = i * 2048 + wv * 512;          // ushort units
        if (c0 < FR_KS) {
#if __has_builtin(__builtin_amdgcn_global_load_lds)
            __builtin_amdgcn_global_load_lds(
                (const __attribute__((address_space(1))) unsigned int*)(gb + c0 + lane * 8),
                (__attribute__((address_space(3))) unsigned int*)(dst + c0),
                16, 0, 0);
#else
            *(uint4*)(dst + c0 + (size_t)lane * 8) = *(const uint4*)(gb + c0 + (size_t)lane * 8);
#endif
        }
    }
}

// ---------------------------------------------------------------------------
// xg = x @ W_ih^T (+ bias, fused into epilogue), split-bf16 MFMA.
// Structure unchanged from R6 except the bias add at C-write.
// ---------------------------------------------------------------------------
__global__ __launch_bounds__(256, 2) void gemm_xg(
    const float* __restrict__ x, const int* __restrict__ mask,
    const float* __restrict__ b_ih, const float* __restrict__ b_hh,
    float* __restrict__ xg)
{
    __shared__ ushort Bs[2][FR_KS];                  // 53,248 B
    __shared__ int tile_sh;
    const int tid  = threadIdx.x;
    const int wv   = tid >> 6;
    const int lane = tid & 63;
    const int lr   = lane & 15;
    const int kch  = (lane >> 4) * 8;

    for (;;) {
        if (tid == 0) tile_sh = atomicAdd(&g_counter, 1);
        __syncthreads();
        const int tile = tile_sh;
        __syncthreads();
        if (tile >= NTILES) return;

        const int row0 = tile * BROWS;
        const int b    = row0 >> 9;
        const int t0   = row0 & (S_LEN - 1);
        if (mask[b * S_LEN + t0] == 0) continue;     // whole tile past length[b]
        const bool live = mask[b * S_LEN + t0 + wv * 32] != 0;

        const int r0 = row0 + wv * 32;
        const float* xr0 = x + (size_t)(r0 + lr) * D_IN;
        const float* xr1 = xr0 + (size_t)16 * D_IN;

        f32x4 acc0[NCT], acc1[NCT];
#pragma unroll
        for (int i = 0; i < NCT; ++i) {
            acc0[i] = (f32x4){0.f, 0.f, 0.f, 0.f};
            acc1[i] = (f32x4){0.f, 0.f, 0.f, 0.f};
        }
        float4 ac0 = {0,0,0,0}, ac1 = {0,0,0,0}, ac2 = {0,0,0,0}, ac3 = {0,0,0,0};
        float4 an0 = {0,0,0,0}, an1 = {0,0,0,0}, an2 = {0,0,0,0}, an3 = {0,0,0,0};

        stage_b(0, Bs[0], wv, lane);
        if (live) {
            ac0 = *(const float4*)(xr0 + kch);
            ac1 = *(const float4*)(xr0 + kch + 4);
            ac2 = *(const float4*)(xr1 + kch);
            ac3 = *(const float4*)(xr1 + kch + 4);
        }
        __syncthreads();                             // Bs[0] staged & drained

        for (int ks = 0; ks < KSTEPS; ++ks) {
            if (ks < KSTEPS - 1) {
                stage_b(ks + 1, Bs[(ks + 1) & 1], wv, lane);
                if (live) {
                    const int k1 = (ks + 1) * 32 + kch;
                    an0 = *(const float4*)(xr0 + k1);
                    an1 = *(const float4*)(xr0 + k1 + 4);
                    an2 = *(const float4*)(xr1 + k1);
                    an3 = *(const float4*)(xr1 + k1 + 4);
                }
            }
            if (live) {
                uint4 h0, l0, h1, l1;
                pack2(ac0.x, ac0.y, h0.x, l0.x); pack2(ac0.z, ac0.w, h0.y, l0.y);
                pack2(ac1.x, ac1.y, h0.z, l0.z); pack2(ac1.z, ac1.w, h0.w, l0.w);
                pack2(ac2.x, ac2.y, h1.x, l1.x); pack2(ac2.z, ac2.w, h1.y, l1.y);
                pack2(ac3.x, ac3.y, h1.z, l1.z); pack2(ac3.z, ac3.w, h1.w, l1.w);
                s16x8 A0h = *(s16x8*)&h0, A0l = *(s16x8*)&l0;
                s16x8 A1h = *(s16x8*)&h1, A1l = *(s16x8*)&l1;
                const ushort* bp = &Bs[ks & 1][lane * 8];
#pragma unroll
                for (int ct = 0; ct < NCT; ++ct) {
                    s16x8 Bh = *(const s16x8*)(bp + ct * 1024);
                    s16x8 Bl = *(const s16x8*)(bp + ct * 1024 + 512);
                    acc0[ct] = __builtin_amdgcn_mfma_f32_16x16x32_bf16(A0h, Bh, acc0[ct], 0, 0, 0);
                    acc0[ct] = __builtin_amdgcn_mfma_f32_16x16x32_bf16(A0l, Bh, acc0[ct], 0, 0, 0);
                    acc0[ct] = __builtin_amdgcn_mfma_f32_16x16x32_bf16(A0h, Bl, acc0[ct], 0, 0, 0);
                    acc1[ct] = __builtin_amdgcn_mfma_f32_16x16x32_bf16(A1h, Bh, acc1[ct], 0, 0, 0);
                    acc1[ct] = __builtin_amdgcn_mfma_f32_16x16x32_bf16(A1l, Bh, acc1[ct], 0, 0, 0);
                    acc1[ct] = __builtin_amdgcn_mfma_f32_16x16x32_bf16(A1h, Bl, acc1[ct], 0, 0, 0);
                }
            }
            ac0 = an0; ac1 = an1; ac2 = an2; ac3 = an3;
            __syncthreads();                         // readers done; stage(ks+1) drained
        }

        if (live) {
            const int orow = r0 + (lane >> 4) * 4;
            const int ocol = lane & 15;
#pragma unroll
            for (int ct = 0; ct < NCT; ++ct) {
                const int col = ct * 16 + ocol;
                if (col < G4) {
                    const float bias = b_ih[col] + b_hh[col];
#pragma unroll
                    for (int e = 0; e < 4; ++e) {
                        xg[(size_t)(orow + e) * G4 + col]      = acc0[ct][e] + bias;
                        xg[(size_t)(orow + 16 + e) * G4 + col] = acc1[ct][e] + bias;
                    }
                }
            }
        }
    }
}

// ---------------------------------------------------------------------------
// LSTM scan: ONE WAVE per batch, zero barriers, issue-bound. This round:
// rcp/exp2 activations (no IEEE divides), bias pre-folded into xg,
// pointer-increment prefetch with immediate offsets.
// ---------------------------------------------------------------------------
#define REP25(M) M(0) M(1) M(2) M(3) M(4) M(5) M(6) M(7) M(8) M(9) \
                 M(10) M(11) M(12) M(13) M(14) M(15) M(16) M(17) M(18) M(19) \
                 M(20) M(21) M(22) M(23) M(24)

__device__ __forceinline__ unsigned pk2f16(float a, float b) {
#if __has_builtin(__builtin_amdgcn_cvt_pkrtz)
    return __builtin_bit_cast(unsigned, __builtin_amdgcn_cvt_pkrtz(a, b));
#else
    f16x2 v = {(_Float16)a, (_Float16)b};
    return __builtin_bit_cast(unsigned, v);
#endif
}

#if __has_builtin(__builtin_amdgcn_fdot2)
#define FD(hu_, wu_, cc_) __builtin_amdgcn_fdot2( \
    __builtin_bit_cast(f16x2, (hu_)), __builtin_bit_cast(f16x2, (wu_)), (cc_), false)
#else
#define FD(hu_, wu_, cc_) ((cc_) \
    + (float)__builtin_bit_cast(f16x2, (hu_))[0] * (float)__builtin_bit_cast(f16x2, (wu_))[0] \
    + (float)__builtin_bit_cast(f16x2, (hu_))[1] * (float)__builtin_bit_cast(f16x2, (wu_))[1])
#endif

__global__ __launch_bounds__(64, 1) void lstm_scan(
    const float* __restrict__ xgp, const int* __restrict__ mask,
    const float* __restrict__ W_hh, const float* __restrict__ W_cls,
    const float* __restrict__ b_cls, float* __restrict__ out)
{
    const int b = blockIdx.x;
    const int l = threadIdx.x;

    int s = 0;
#pragma unroll
    for (int k = 0; k < 8; ++k) s += mask[b * S_LEN + l + 64 * k];
#pragma unroll
    for (int off = 1; off < 64; off <<= 1) s += __shfl_xor(s, off, 64);
    const int len = s;                               // >= 1

    const bool act = (l < H_DIM);
    const int  ll  = act ? l : 0;                    // keep W_hh rows in-bounds
    const float* wr0 = W_hh + (size_t)ll * H_DIM;
    const float* wr1 = W_hh + (size_t)(50 + ll) * H_DIM;
    const float* wr2 = W_hh + (size_t)(100 + ll) * H_DIM;
    const float* wr3 = W_hh + (size_t)(150 + ll) * H_DIM;

#define WDECL(q) unsigned wi_##q, wf_##q, wg_##q, wo_##q;
    REP25(WDECL)
#undef WDECL
#define WLOAD(q) \
    wi_##q = pk2f16(wr0[2*q], wr0[2*q+1]); \
    wf_##q = pk2f16(wr1[2*q], wr1[2*q+1]); \
    wg_##q = pk2f16(wr2[2*q], wr2[2*q+1]); \
    wo_##q = pk2f16(wr3[2*q], wr3[2*q+1]);
    REP25(WLOAD)
#undef WLOAD
#define WPIN(q) asm volatile("" : "+v"(wi_##q), "+v"(wf_##q), "+v"(wg_##q), "+v"(wo_##q));
    REP25(WPIN)
#undef WPIN

    float h = 0.f, c = 0.f;
    const float* xgb = xgp + (size_t)b * S_LEN * G4;

    // initial 4-deep prefetch (bias already folded into xg by the GEMM)
    auto ld0 = [&](int t, float& xi, float& xf, float& xq, float& xo) {
        if (act && t < len) {
            const float* pp = xgb + (size_t)t * G4 + l;
            xi = pp[0]; xf = pp[50]; xq = pp[100]; xo = pp[150];
        }
    };
    float xiA=0,xfA=0,xqA=0,xoA=0, xiB=0,xfB=0,xqB=0,xoB=0;
    float xiC=0,xfC=0,xqC=0,xoC=0, xiD=0,xfD=0,xqD=0,xoD=0;
    ld0(0, xiA, xfA, xqA, xoA); ld0(1, xiB, xfB, xqB, xoB);
    ld0(2, xiC, xfC, xqC, xoC); ld0(3, xiD, xfD, xqD, xoD);

    const float* pref = xgb + 4 * G4 + l;            // row t+4 base at step t=0

    auto step = [&](int t, float& xi, float& xf, float& xq, float& xo) {
        // build this lane's h-pair (h[2l], h[2l+1]); broadcast via readlane
        int pa = __builtin_amdgcn_ds_bpermute(8 * l,     __float_as_int(h));
        int pb = __builtin_amdgcn_ds_bpermute(8 * l + 4, __float_as_int(h));
        unsigned hu = pk2f16(__int_as_float(pa), __int_as_float(pb));

        float ai = xi, af = xf, aq = xq, ao = xo;    // bias pre-folded
        if (act && t + 4 < len) {                    // prefetch into this set
            xi = pref[0]; xf = pref[50]; xq = pref[100]; xo = pref[150];
        }
        pref += G4;
#define DOT(q) { \
        unsigned r_ = (unsigned)__builtin_amdgcn_readlane((int)hu, q); \
        ai = FD(r_, wi_##q, ai); af = FD(r_, wf_##q, af); \
        aq = FD(r_, wg_##q, aq); ao = FD(r_, wo_##q, ao); }
        REP25(DOT)
#undef DOT
        float ig = fsigmoid(ai), fg = fsigmoid(af);
        float gg = ftanh(aq),    og = fsigmoid(ao);
        if (act) {
            c = fg * c + ig * gg;
            h = og * ftanh(c);
        }
    };

    int t = 0;
    while (t < len) {
        step(t, xiA, xfA, xqA, xoA); ++t; if (t >= len) break;
        step(t, xiB, xfB, xqB, xoB); ++t; if (t >= len) break;
        step(t, xiC, xfC, xqC, xoC); ++t; if (t >= len) break;
        step(t, xiD, xfD, xqD, xoD); ++t;
    }

    float p0 = act ? h * W_cls[l]          : 0.f;
    float p1 = act ? h * W_cls[H_DIM + l]  : 0.f;
#pragma unroll
    for (int off = 1; off < 64; off <<= 1) {
        p0 += __shfl_xor(p0, off, 64);
        p1 += __shfl_xor(p1, off, 64);
    }
    if (l == 0) {
        out[2 * b]     = p0 + b_cls[0];
        out[2 * b + 1] = p1 + b_cls[1];
    }
}

extern "C" void kernel_launch(void* const* d_in, const int* in_sizes, int n_in,
                              void* d_out, int out_size, void* d_ws, size_t ws_size,
                              hipStream_t stream) {
    const float* x     = (const float*)d_in[0];
    const int*   mask  = (const int*)  d_in[1];
    const float* W_ih  = (const float*)d_in[2];
    const float* W_hh  = (const float*)d_in[3];
    const float* b_ih  = (const float*)d_in[4];
    const float* b_hh  = (const float*)d_in[5];
    const float* W_cls = (const float*)d_in[6];
    const float* b_cls = (const float*)d_in[7];
    float* out = (float*)d_out;
    float* xg  = (float*)d_ws;                       // 104.9 MB

    hipLaunchKernelGGL(prep_w, dim3(156), dim3(256), 0, stream, W_ih);
    hipLaunchKernelGGL(gemm_xg, dim3(512), dim3(256), 0, stream, x, mask, b_ih, b_hh, xg);
    hipLaunchKernelGGL(lstm_scan, dim3(256), dim3(64), 0, stream,
                       xg, mask, W_hh, W_cls, b_cls, out);
}